// Round 1
// 294.567 us; speedup vs baseline: 1.0869x; 1.0869x over previous
//
#include <hip/hip_runtime.h>
#include <math.h>

#define NT      256
#define NSYMS   824
#define NPILOT  9

// padded LDS index: +1 element per 16 to break power-of-2 bank strides
#define PADIDX(k) ((k) + ((k) >> 4))

// f32(2*pi/1024): exact value of numpy's float32 ramp constant
#define C32_TWOPI_1024  6.1359233222901821136474609375e-3f

__device__ __forceinline__ float2 cmulf(float2 a, float2 b) {
    return make_float2(a.x * b.x - a.y * b.y, a.x * b.y + a.y * b.x);
}

// one radix-4 Stockham DIF stage; T2 = 2*t, s = 4^t = 1<<T2
template <int T2>
__device__ __forceinline__ void r4_stage(const float2* __restrict__ src,
                                         float2* __restrict__ dst,
                                         const float2* __restrict__ W,
                                         int i) {
    const int s = 1 << T2;
    const int r = i & (s - 1);
    const int p = i & ~(s - 1);            // twiddle base exponent (multiple of s)
    const int pb = PADIDX(i);
    float2 a = src[pb];
    float2 b = src[pb + 272];              // PADIDX(i+256) = PADIDX(i)+272
    float2 c = src[pb + 544];
    float2 d = src[pb + 816];
    float2 w1 = W[PADIDX(p)];
    float2 w2 = W[PADIDX(2 * p)];          // 3p <= 756 -> W needs only 816 padded entries
    float2 w3 = W[PADIDX(3 * p)];
    float2 t0  = make_float2(a.x + c.x, a.y + c.y);
    float2 t1  = make_float2(a.x - c.x, a.y - c.y);
    float2 t2c = make_float2(b.x + d.x, b.y + d.y);
    float2 t3  = make_float2(b.x - d.x, b.y - d.y);
    float2 y0  = make_float2(t0.x + t2c.x, t0.y + t2c.y);
    float2 e1  = make_float2(t1.x + t3.y, t1.y - t3.x);   // t1 - i*t3
    float2 e2  = make_float2(t0.x - t2c.x, t0.y - t2c.y);
    float2 e3  = make_float2(t1.x - t3.y, t1.y + t3.x);   // t1 + i*t3
    const int j0 = ((i >> T2) << (T2 + 2)) | r;
    dst[PADIDX(j0)]         = y0;
    dst[PADIDX(j0 + s)]     = cmulf(w1, e1);
    dst[PADIDX(j0 + 2 * s)] = cmulf(w2, e2);
    dst[PADIDX(j0 + 3 * s)] = cmulf(w3, e3);
}

// LDS budget (target: 5 blocks/CU, i.e. <= 32768 B after 512-B granule):
//   T256 4096 + u_s 4096 + bufA 8704 + bufB 8704 + W 6528 + ang 72 = 32200 -> 32256
__global__ __launch_bounds__(NT, 5) void ofdm_kernel(const float* __restrict__ in,
                                                     float* __restrict__ out) {
    __shared__ double2 T256[256];     // f64 twiddle base quadrant: exp(-2pi*i*k/1024), k<256
    __shared__ double2 u_s[NT];       // radix-4 folded input for pilot DFT
    __shared__ float2  bufA[1088];
    __shared__ float2  bufB[1088];
    __shared__ float2  W[816];        // f32 twiddles, exponents 0..756 only (4th quadrant dead)
    __shared__ double  ang[NPILOT];

    const int row = blockIdx.x;       // 0..16383
    const int tid = threadIdx.x;

    // ---- load 1024 complex samples at complex offset 128 (CP/2) ----
    const float2* rin2 = (const float2*)(in + (size_t)row * 2560) + 128;
    float2 v0 = rin2[tid];
    float2 v1 = rin2[tid + 256];
    float2 v2 = rin2[tid + 512];
    float2 v3 = rin2[tid + 768];

    // ---- pilot fold (f64): u_t = x_t + i*x_{t+256} - x_{t+512} - i*x_{t+768}
    // valid because pilot FFT bins K = (jj+512)&1023 satisfy K mod 4 == 3,
    // so w^{256*K*delta} = i^delta.
    double ux = ((double)v0.x - (double)v2.x) - ((double)v1.y - (double)v3.y);
    double uy = ((double)v0.y - (double)v2.y) + ((double)v1.x - (double)v3.x);

    // ---- twiddle tables: 1 f64 sincos/thread; T compressed to one quadrant ----
    {
        double sn, cs;
        sincos((double)tid * -6.1359231515425649189e-3, &sn, &cs);  // -2pi/1024
        T256[tid] = make_double2(cs, sn);
        float cf = (float)cs, sf = (float)sn;
        W[PADIDX(tid)]       = make_float2(cf, sf);
        W[PADIDX(tid + 256)] = make_float2(sf, -cf);    // *(-i)
        W[PADIDX(tid + 512)] = make_float2(-cf, -sf);   // *(-1)
        // exponent >= 768 never read by any stage (3p <= 756): quadrant dropped
    }

    bufA[PADIDX(tid)]       = v0;
    bufA[PADIDX(tid + 256)] = v1;
    bufA[PADIDX(tid + 512)] = v2;
    bufA[PADIDX(tid + 768)] = v3;
    u_s[tid] = make_double2(ux, uy);
    __syncthreads();

    // ---- pilot DFT: pilot p on lanes [16p,16p+16), 16 interleaved terms each;
    // partials reduced via shfl (no LDS partial array, no separate finalize phase).
    if (tid < 16 * NPILOT) {
        const int p  = tid >> 4;
        const int g  = tid & 15;
        const int jj = 95 + 100 * p;
        const int K  = (jj + 512) & 1023;     // rolled FFT bin (odd for all pilots)
        int idx = (K * g) & 1023;
        const int step = (K * 16) & 1023;
        double2 acc = make_double2(0.0, 0.0);
        #pragma unroll
        for (int m = 0; m < 16; m++) {
            double2 uu = u_s[g + 16 * m];     // adjacent lanes -> consecutive entries
            double2 w  = T256[idx & 255];
            // exact quadrant rotation by (-i)^(idx>>8): sign/swap only, bit-identical
            // to the former 1024-entry f64 table
            const int q = idx >> 8;
            double wx = w.x, wy = w.y;
            if (q & 1) { double t = wx; wx = wy; wy = -t; }
            if (q & 2) { wx = -wx; wy = -wy; }
            acc.x += wx * uu.x - wy * uu.y;
            acc.y += wx * uu.y + wy * uu.x;
            idx = (idx + step) & 1023;
        }
        // butterfly reduce across the 16-lane pilot group (partners always active)
        #pragma unroll
        for (int off = 1; off < 16; off <<= 1) {
            acc.x += __shfl_xor(acc.x, off, 64);
            acc.y += __shfl_xor(acc.y, off, 64);
        }
        if (g == 0) {
            // bit-exact emulation of numpy's complex64 ramp (round-4 formula)
            float th32 = (float)(128 * jj) * C32_TWOPI_1024;
            double sn, cs;
            sincos((double)th32, &sn, &cs);
            double csf = (double)(float)cs;
            double snf = (double)(float)sn;
            double re = acc.x * csf - acc.y * snf;
            double im = acc.x * snf + acc.y * csf;
            ang[p] = atan2(im, re);
        }
    }
    // ---- FFT stage 0 (A->B) in the same phase ----
    r4_stage<0>(bufA, bufB, W, tid);
    __syncthreads();
    r4_stage<2>(bufB, bufA, W, tid);
    __syncthreads();
    r4_stage<4>(bufA, bufB, W, tid);
    __syncthreads();
    r4_stage<6>(bufB, bufA, W, tid);          // penultimate result in bufA
    __syncthreads();

    // ---- wrapped-diff mean (every thread, f64, unchanged) ----
    double mn;
    {
        double sum = 0.0;
        double prev = ang[0];
        #pragma unroll
        for (int k = 1; k < NPILOT; k++) {
            double cur = ang[k];
            double a = cur - prev;
            if (a > 3.14159265358979323846)       a -= 6.28318530717958647693;
            else if (a < -3.14159265358979323846) a += 6.28318530717958647693;
            sum += a;
            prev = cur;
        }
        mn = sum * 0.125;
    }

    // ---- fused final stage (s=256, unit twiddles) + correction + gather ----
    // thread i's butterfly outputs are bins {i, i+256, i+512, i+768}; after the
    // ^512 roll these are exactly the four jj == i (mod 256). Inverse data map:
    // valid iff 96 <= jj <= 927 and (jj-95)%100 != 0; d = jj - 96 - (jj-96)/100.
    {
        const int pb = PADIDX(tid);
        float2 a = bufA[pb];
        float2 b = bufA[pb + 272];
        float2 c = bufA[pb + 544];
        float2 d = bufA[pb + 816];
        float2 t0  = make_float2(a.x + c.x, a.y + c.y);
        float2 t1  = make_float2(a.x - c.x, a.y - c.y);
        float2 t2c = make_float2(b.x + d.x, b.y + d.y);
        float2 t3  = make_float2(b.x - d.x, b.y - d.y);
        float2 y0  = make_float2(t0.x + t2c.x, t0.y + t2c.y);  // bin tid      -> jj = tid+512
        float2 y1  = make_float2(t1.x + t3.y, t1.y - t3.x);    // bin tid+256  -> jj = tid+768
        float2 y2  = make_float2(t0.x - t2c.x, t0.y - t2c.y);  // bin tid+512  -> jj = tid
        float2 y3  = make_float2(t1.x - t3.y, t1.y + t3.x);    // bin tid+768  -> jj = tid+256

        float2* rout = (float2*)(out + (size_t)row * (2 * NSYMS));
        float2 ys[4] = { y2, y3, y0, y1 };     // ordered by jj = tid, tid+256, tid+512, tid+768
        #pragma unroll
        for (int k = 0; k < 4; k++) {
            const int jj = tid + 256 * k;
            if (jj >= 96 && jj <= 927 && ((jj - 95) % 100) != 0) {
                const int dd = jj - 96 - (jj - 96) / 100;
                float2 z = ys[k];
                float th32 = (float)(128 * jj) * C32_TWOPI_1024;
                float ph = th32 - (float)(mn * 0.01 * (double)jj);
                float sn, cs;
                __sincosf(ph, &sn, &cs);
                rout[dd] = make_float2(z.x * cs - z.y * sn,
                                       z.x * sn + z.y * cs);
            }
        }
    }
}

extern "C" void kernel_launch(void* const* d_in, const int* in_sizes, int n_in,
                              void* d_out, int out_size, void* d_ws, size_t ws_size,
                              hipStream_t stream) {
    const float* in = (const float*)d_in[0];
    float* out = (float*)d_out;
    ofdm_kernel<<<dim3(16 * 1024), dim3(NT), 0, stream>>>(in, out);
}

// Round 2
// 281.486 us; speedup vs baseline: 1.1374x; 1.0465x over previous
//
#include <hip/hip_runtime.h>
#include <math.h>

#define NT      256
#define NSYMS   824
#define NPILOT  9

// padded LDS index: +1 element per 16 to break power-of-2 bank strides
#define PADIDX(k) ((k) + ((k) >> 4))

// f32(2*pi/1024): exact value of numpy's float32 ramp constant
#define C32_TWOPI_1024  6.1359233222901821136474609375e-3f

__device__ __forceinline__ float2 cmulf(float2 a, float2 b) {
    return make_float2(a.x * b.x - a.y * b.y, a.x * b.y + a.y * b.x);
}

// ---- in-place radix-4 DIF stage, span L = 4*LM, twiddle scale F = 1024/L ----
// butterfly i: slots base + {0,LM,2LM,3LM}, base = (i/LM)*4LM + (i%LM).
// Each thread owns its 4 slots (read+write), so in-place is race-free per stage.
// Twiddle exponents: e1 = F*r < 256, e2 = 2F*r < 512, e3 = 3F*r < 768 -> a
// 256-entry quadrant table + exact (-i)^q sign/swap rotation suffices.
template <int LM, int F>
__device__ __forceinline__ void dif_stage(float2* __restrict__ buf,
                                          const float2* __restrict__ W256,
                                          int i) {
    const int r = i & (LM - 1);
    const int base = ((i & ~(LM - 1)) << 2) | r;
    float2 a = buf[PADIDX(base)];
    float2 b = buf[PADIDX(base + LM)];
    float2 c = buf[PADIDX(base + 2 * LM)];
    float2 d = buf[PADIDX(base + 3 * LM)];
    float2 t0 = make_float2(a.x + c.x, a.y + c.y);
    float2 t1 = make_float2(a.x - c.x, a.y - c.y);
    float2 t2 = make_float2(b.x + d.x, b.y + d.y);
    float2 t3 = make_float2(b.x - d.x, b.y - d.y);
    float2 y0 = make_float2(t0.x + t2.x, t0.y + t2.y);
    float2 y1 = make_float2(t1.x + t3.y, t1.y - t3.x);   // t1 - i*t3
    float2 y2 = make_float2(t0.x - t2.x, t0.y - t2.y);
    float2 y3 = make_float2(t1.x - t3.y, t1.y + t3.x);   // t1 + i*t3
    const int e1 = F * r;                // < 256: no rotation ever needed
    const int e2 = 2 * F * r;            // < 512
    const int e3 = 3 * F * r;            // < 768
    float2 w1 = W256[PADIDX(e1)];
    float2 w2 = W256[PADIDX(e2 & 255)];
    if (e2 & 256) w2 = make_float2(w2.y, -w2.x);          // * (-i), exact
    float2 w3 = W256[PADIDX(e3 & 255)];
    {
        const int q = e3 >> 8;
        if (q == 1)      w3 = make_float2(w3.y, -w3.x);   // * (-i)
        else if (q == 2) w3 = make_float2(-w3.x, -w3.y);  // * (-1)
    }
    buf[PADIDX(base)]          = y0;
    buf[PADIDX(base + LM)]     = cmulf(w1, y1);
    buf[PADIDX(base + 2 * LM)] = cmulf(w2, y2);
    buf[PADIDX(base + 3 * LM)] = cmulf(w3, y3);
}

// ---- one-time table build: identical for every row, so do it ONCE per launch
// into workspace instead of 16384x per-block f64 sincos.
__global__ void table_init(double2* __restrict__ Tg, float2* __restrict__ Wg) {
    const int t = threadIdx.x;
    double sn, cs;
    sincos((double)t * -6.1359231515425649189e-3, &sn, &cs);  // -2pi/1024
    Tg[t] = make_double2(cs, sn);                 // f64 quadrant (pilot path)
    Wg[t] = make_float2((float)cs, (float)sn);    // f32 quadrant (FFT path)
}

// LDS budget: T256 4096 + u_s 4096 + buf 8704 + W256 2176 + ang 72 = 19144 B
// -> 8 blocks/CU (8*19144 = 153152 <= 163840) = 32 waves = 100% occupancy.
__global__ __launch_bounds__(NT, 8) void ofdm_kernel(const float* __restrict__ in,
                                                     float* __restrict__ out,
                                                     const double2* __restrict__ Tg,
                                                     const float2* __restrict__ Wg) {
    __shared__ double2 T256[256];     // f64 twiddle quadrant: exp(-2pi*i*k/1024), k<256
    __shared__ double2 u_s[NT];       // radix-4 folded input for pilot DFT
    __shared__ float2  buf[1088];     // single in-place FFT buffer (padded)
    __shared__ float2  W256[272];     // f32 twiddle quadrant (padded)
    __shared__ double  ang[NPILOT];

    const int row = blockIdx.x;       // 0..16383
    const int tid = threadIdx.x;

    // ---- load 1024 complex samples at complex offset 128 (CP/2) ----
    const float2* rin2 = (const float2*)(in + (size_t)row * 2560) + 128;
    float2 v0 = rin2[tid];
    float2 v1 = rin2[tid + 256];
    float2 v2 = rin2[tid + 512];
    float2 v3 = rin2[tid + 768];

    // ---- load twiddle tables (coalesced, L2/LIC-broadcast) ----
    T256[tid] = Tg[tid];
    W256[PADIDX(tid)] = Wg[tid];

    // ---- pilot fold (f64): u_t = x_t + i*x_{t+256} - x_{t+512} - i*x_{t+768}
    // valid because pilot FFT bins K = (jj+512)&1023 satisfy K mod 4 == 3,
    // so w^{256*K*delta} = i^delta.
    double ux = ((double)v0.x - (double)v2.x) - ((double)v1.y - (double)v3.y);
    double uy = ((double)v0.y - (double)v2.y) + ((double)v1.x - (double)v3.x);

    buf[PADIDX(tid)]       = v0;
    buf[PADIDX(tid + 256)] = v1;
    buf[PADIDX(tid + 512)] = v2;
    buf[PADIDX(tid + 768)] = v3;
    u_s[tid] = make_double2(ux, uy);
    __syncthreads();

    // ---- pilot DFT: pilot p on lanes [16p,16p+16), 16 interleaved terms each;
    // partials reduced via shfl; overlapped with FFT stage 1 below.
    if (tid < 16 * NPILOT) {
        const int p  = tid >> 4;
        const int g  = tid & 15;
        const int jj = 95 + 100 * p;
        const int K  = (jj + 512) & 1023;     // rolled FFT bin (odd for all pilots)
        int idx = (K * g) & 1023;
        const int step = (K * 16) & 1023;
        double2 acc = make_double2(0.0, 0.0);
        #pragma unroll
        for (int m = 0; m < 16; m++) {
            double2 uu = u_s[g + 16 * m];     // adjacent lanes -> consecutive entries
            double2 w  = T256[idx & 255];
            // exact quadrant rotation by (-i)^(idx>>8): sign/swap only
            const int q = idx >> 8;
            double wx = w.x, wy = w.y;
            if (q & 1) { double t = wx; wx = wy; wy = -t; }
            if (q & 2) { wx = -wx; wy = -wy; }
            acc.x += wx * uu.x - wy * uu.y;
            acc.y += wx * uu.y + wy * uu.x;
            idx = (idx + step) & 1023;
        }
        // butterfly reduce across the 16-lane pilot group (partners always active)
        #pragma unroll
        for (int off = 1; off < 16; off <<= 1) {
            acc.x += __shfl_xor(acc.x, off, 64);
            acc.y += __shfl_xor(acc.y, off, 64);
        }
        if (g == 0) {
            // bit-exact emulation of numpy's complex64 ramp (round-4 formula)
            float th32 = (float)(128 * jj) * C32_TWOPI_1024;
            double sn, cs;
            sincos((double)th32, &sn, &cs);
            double csf = (double)(float)cs;
            double snf = (double)(float)sn;
            double re = acc.x * csf - acc.y * snf;
            double im = acc.x * snf + acc.y * csf;
            ang[p] = atan2(im, re);
        }
    }
    // ---- in-place DIF FFT: 4 staged butterflies + fused final stage ----
    dif_stage<256, 1>(buf, W256, tid);        // span 1024
    __syncthreads();
    dif_stage<64, 4>(buf, W256, tid);         // span 256
    __syncthreads();
    dif_stage<16, 16>(buf, W256, tid);        // span 64
    __syncthreads();
    dif_stage<4, 64>(buf, W256, tid);         // span 16
    __syncthreads();

    // ---- wrapped-diff mean (every thread, f64, unchanged) ----
    double mn;
    {
        double sum = 0.0;
        double prev = ang[0];
        #pragma unroll
        for (int k = 1; k < NPILOT; k++) {
            double cur = ang[k];
            double a = cur - prev;
            if (a > 3.14159265358979323846)       a -= 6.28318530717958647693;
            else if (a < -3.14159265358979323846) a += 6.28318530717958647693;
            sum += a;
            prev = cur;
        }
        mn = sum * 0.125;
    }

    // ---- fused final stage (span 4, unit twiddles) + correction + gather ----
    // After 5 DIF stages output is base-4 digit-reversed: slot n holds X[rev(n)].
    // Thread t butterflies slots {4t..4t+3} (contiguous, same padded 16-group),
    // producing bins {R, R+256, R+512, R+768} with R = rev4(t). After the ^512
    // roll these are the four jj == R (mod 256). Inverse data map: valid iff
    // 96 <= jj <= 927 and (jj-95)%100 != 0; d = jj - 96 - (jj-96)/100.
    {
        const int pb = PADIDX(4 * tid);       // 4t..4t+3 never cross a pad group
        float2 a = buf[pb];
        float2 b = buf[pb + 1];
        float2 c = buf[pb + 2];
        float2 d = buf[pb + 3];
        float2 t0 = make_float2(a.x + c.x, a.y + c.y);
        float2 t1 = make_float2(a.x - c.x, a.y - c.y);
        float2 t2 = make_float2(b.x + d.x, b.y + d.y);
        float2 t3 = make_float2(b.x - d.x, b.y - d.y);
        float2 y0 = make_float2(t0.x + t2.x, t0.y + t2.y);  // bin R      -> jj = R+512
        float2 y1 = make_float2(t1.x + t3.y, t1.y - t3.x);  // bin R+256  -> jj = R+768
        float2 y2 = make_float2(t0.x - t2.x, t0.y - t2.y);  // bin R+512  -> jj = R
        float2 y3 = make_float2(t1.x - t3.y, t1.y + t3.x);  // bin R+768  -> jj = R+256

        const int R = ((tid & 3) << 6) | (((tid >> 2) & 3) << 4) |
                      (((tid >> 4) & 3) << 2) | ((tid >> 6) & 3);

        float2* rout = (float2*)(out + (size_t)row * (2 * NSYMS));
        float2 ys[4] = { y2, y3, y0, y1 };    // ordered by jj = R, R+256, R+512, R+768
        #pragma unroll
        for (int k = 0; k < 4; k++) {
            const int jj = R + 256 * k;
            if (jj >= 96 && jj <= 927 && ((jj - 95) % 100) != 0) {
                const int dd = jj - 96 - (jj - 96) / 100;
                float2 z = ys[k];
                float th32 = (float)(128 * jj) * C32_TWOPI_1024;
                float ph = th32 - (float)(mn * 0.01 * (double)jj);
                float sn, cs;
                __sincosf(ph, &sn, &cs);
                rout[dd] = make_float2(z.x * cs - z.y * sn,
                                       z.x * sn + z.y * cs);
            }
        }
    }
}

extern "C" void kernel_launch(void* const* d_in, const int* in_sizes, int n_in,
                              void* d_out, int out_size, void* d_ws, size_t ws_size,
                              hipStream_t stream) {
    const float* in = (const float*)d_in[0];
    float* out = (float*)d_out;
    double2* Tg = (double2*)d_ws;                       // 256 * 16 B = 4096 B
    float2*  Wg = (float2*)((char*)d_ws + 4096);        // 256 *  8 B = 2048 B
    table_init<<<dim3(1), dim3(256), 0, stream>>>(Tg, Wg);
    ofdm_kernel<<<dim3(16 * 1024), dim3(NT), 0, stream>>>(in, out, Tg, Wg);
}

// Round 3
// 267.519 us; speedup vs baseline: 1.1967x; 1.0522x over previous
//
#include <hip/hip_runtime.h>
#include <math.h>

#define NT      256
#define NSYMS   824
#define NPILOT  9

// padded LDS index: +1 element per 16 to break power-of-2 bank strides
#define PADIDX(k) ((k) + ((k) >> 4))

// f32(2*pi/1024): exact value of numpy's float32 ramp constant
#define C32_TWOPI_1024  6.1359233222901821136474609375e-3f

__device__ __forceinline__ float2 cmulf(float2 a, float2 b) {
    return make_float2(a.x * b.x - a.y * b.y, a.x * b.y + a.y * b.x);
}

// ---- in-place radix-4 DIF stage, span L = 4*LM, twiddle scale F = 1024/L ----
// butterfly i: slots base + {0,LM,2LM,3LM}, base = (i/LM)*4LM + (i%LM).
// Each thread owns its 4 slots (read+write), so in-place is race-free per stage.
// Twiddle exponents: e1 = F*r < 256, e2 = 2F*r < 512, e3 = 3F*r < 768 -> a
// 256-entry quadrant table + exact (-i)^q sign/swap rotation suffices.
template <int LM, int F>
__device__ __forceinline__ void dif_stage(float2* __restrict__ buf,
                                          const float2* __restrict__ W256,
                                          int i) {
    const int r = i & (LM - 1);
    const int base = ((i & ~(LM - 1)) << 2) | r;
    float2 a = buf[PADIDX(base)];
    float2 b = buf[PADIDX(base + LM)];
    float2 c = buf[PADIDX(base + 2 * LM)];
    float2 d = buf[PADIDX(base + 3 * LM)];
    float2 t0 = make_float2(a.x + c.x, a.y + c.y);
    float2 t1 = make_float2(a.x - c.x, a.y - c.y);
    float2 t2 = make_float2(b.x + d.x, b.y + d.y);
    float2 t3 = make_float2(b.x - d.x, b.y - d.y);
    float2 y0 = make_float2(t0.x + t2.x, t0.y + t2.y);
    float2 y1 = make_float2(t1.x + t3.y, t1.y - t3.x);   // t1 - i*t3
    float2 y2 = make_float2(t0.x - t2.x, t0.y - t2.y);
    float2 y3 = make_float2(t1.x - t3.y, t1.y + t3.x);   // t1 + i*t3
    const int e1 = F * r;                // < 256: no rotation ever needed
    const int e2 = 2 * F * r;            // < 512
    const int e3 = 3 * F * r;            // < 768
    float2 w1 = W256[PADIDX(e1)];
    float2 w2 = W256[PADIDX(e2 & 255)];
    if (e2 & 256) w2 = make_float2(w2.y, -w2.x);          // * (-i), exact
    float2 w3 = W256[PADIDX(e3 & 255)];
    {
        const int q = e3 >> 8;
        if (q == 1)      w3 = make_float2(w3.y, -w3.x);   // * (-i)
        else if (q == 2) w3 = make_float2(-w3.x, -w3.y);  // * (-1)
    }
    buf[PADIDX(base)]          = y0;
    buf[PADIDX(base + LM)]     = cmulf(w1, y1);
    buf[PADIDX(base + 2 * LM)] = cmulf(w2, y2);
    buf[PADIDX(base + 3 * LM)] = cmulf(w3, y3);
}

// ---- one-time table build: identical for every row, so do it ONCE per launch
__global__ void table_init(double2* __restrict__ Tg, float2* __restrict__ Wg) {
    const int t = threadIdx.x;
    double sn, cs;
    sincos((double)t * -6.1359231515425649189e-3, &sn, &cs);  // -2pi/1024
    Tg[t] = make_double2(cs, sn);                 // f64 quadrant (pilot path)
    Wg[t] = make_float2((float)cs, (float)sn);    // f32 quadrant (FFT path)
}

// LDS: T256 4096 + u_s 4096 + buf 8704 + W256 2176 + pr2 144 + mn_s 8 = 19224
// -> 19456 granule -> 8 blocks/CU = 32 waves = 100% occupancy.
__global__ __launch_bounds__(NT, 8) void ofdm_kernel(const float* __restrict__ in,
                                                     float* __restrict__ out,
                                                     const double2* __restrict__ Tg,
                                                     const float2* __restrict__ Wg) {
    __shared__ double2 T256[256];     // f64 twiddle quadrant: exp(-2pi*i*k/1024), k<256
    __shared__ double2 u_s[NT];       // radix-4 folded input for pilot DFT
    __shared__ float2  buf[1088];     // single in-place FFT buffer (padded)
    __shared__ float2  W256[272];     // f32 twiddle quadrant (padded)
    __shared__ double2 pr2[NPILOT];   // reduced pilot sums (pre-finalize)
    __shared__ double  mn_s;          // broadcast wrapped-diff mean

    const int row = blockIdx.x;       // 0..16383
    const int tid = threadIdx.x;

    // ---- load 1024 complex samples at complex offset 128 (CP/2) ----
    const float2* rin2 = (const float2*)(in + (size_t)row * 2560) + 128;
    float2 v0 = rin2[tid];
    float2 v1 = rin2[tid + 256];
    float2 v2 = rin2[tid + 512];
    float2 v3 = rin2[tid + 768];

    // ---- load twiddle tables (coalesced, L2-broadcast) ----
    T256[tid] = Tg[tid];
    W256[PADIDX(tid)] = Wg[tid];

    // ---- pilot fold (f64): u_t = x_t + i*x_{t+256} - x_{t+512} - i*x_{t+768}
    // valid because pilot FFT bins K = (jj+512)&1023 satisfy K mod 4 == 3,
    // so w^{256*K*delta} = i^delta.
    double ux = ((double)v0.x - (double)v2.x) - ((double)v1.y - (double)v3.y);
    double uy = ((double)v0.y - (double)v2.y) + ((double)v1.x - (double)v3.x);

    buf[PADIDX(tid)]       = v0;
    buf[PADIDX(tid + 256)] = v1;
    buf[PADIDX(tid + 512)] = v2;
    buf[PADIDX(tid + 768)] = v3;
    u_s[tid] = make_double2(ux, uy);
    __syncthreads();

    // ---- pilot DFT, folded 256->128: all pilot bins K satisfy K mod 8 in {3,7},
    // so w^{128K} = sigma*(sqrt2/2)*(1+i) exactly, sigma = +1 (K==7 mod 8, even p)
    // or -1 (K==3 mod 8, odd p). u'_s = u_s + sigma*c*(1+i)*u_{s+128}, s < 128;
    // P = sum_{s<128} u'_s w^{Ks}. Halves the MAC loop (16 -> 8 iters).
    // Pilot p on lanes [16p,16p+16) (waves 0-2 only; wave 3 stays light).
    if (tid < 16 * NPILOT) {
        const int p  = tid >> 4;
        const int g  = tid & 15;
        const int jj = 95 + 100 * p;
        const int K  = (jj + 512) & 1023;     // rolled FFT bin
        const double sc = (p & 1) ? -0.70710678118654752440
                                  :  0.70710678118654752440;
        int idx = (K * g) & 1023;
        const int step = (K * 16) & 1023;
        double2 acc = make_double2(0.0, 0.0);
        #pragma unroll
        for (int m = 0; m < 8; m++) {
            const int s = g + 16 * m;         // s < 128
            double2 u0 = u_s[s];              // adjacent lanes -> consecutive
            double2 u1 = u_s[s + 128];
            // u' = u0 + sc*(1+i)*u1 ; (1+i)(a+ib) = (a-b) + i(a+b)
            double upx = u0.x + sc * (u1.x - u1.y);
            double upy = u0.y + sc * (u1.x + u1.y);
            double2 w  = T256[idx & 255];
            // exact quadrant rotation by (-i)^(idx>>8): sign/swap only
            const int q = idx >> 8;
            double wx = w.x, wy = w.y;
            if (q & 1) { double t = wx; wx = wy; wy = -t; }
            if (q & 2) { wx = -wx; wy = -wy; }
            acc.x += wx * upx - wy * upy;
            acc.y += wx * upy + wy * upx;
            idx = (idx + step) & 1023;
        }
        // butterfly reduce across the 16-lane pilot group
        #pragma unroll
        for (int off = 1; off < 16; off <<= 1) {
            acc.x += __shfl_xor(acc.x, off, 64);
            acc.y += __shfl_xor(acc.y, off, 64);
        }
        if (g == 0) pr2[p] = acc;             // raw sum; finalize moved to wave 3
    }
    // ---- FFT stage 1 (span 1024) in the same phase ----
    dif_stage<256, 1>(buf, W256, tid);
    __syncthreads();

    dif_stage<64, 4>(buf, W256, tid);         // span 256
    // ---- pilot finalize + wrapped-diff mean, entirely on wave 3 (SIMD 3 was
    // idle during the pilot phase). sincos/atan2 in f64, formulas unchanged.
    if (tid >= 192) {
        const int p  = tid - 192;
        const int pc = (p < 8) ? p : 8;       // clamp: lanes 9..63 duplicate pilot 8
        double2 acc = pr2[pc];
        const int jj = 95 + 100 * pc;
        // bit-exact emulation of numpy's complex64 ramp (round-4 formula)
        float th32 = (float)(128 * jj) * C32_TWOPI_1024;
        double sn, cs;
        sincos((double)th32, &sn, &cs);
        double csf = (double)(float)cs;
        double snf = (double)(float)sn;
        double re = acc.x * csf - acc.y * snf;
        double im = acc.x * snf + acc.y * csf;
        double a  = atan2(im, re);
        // wrapped diff: lane p takes a_{p+1} - a_p (valid for p<8), then 8-lane sum
        double an = __shfl_down(a, 1, 64);    // all 64 lanes active
        double d  = an - a;
        if (d > 3.14159265358979323846)       d -= 6.28318530717958647693;
        else if (d < -3.14159265358979323846) d += 6.28318530717958647693;
        if (p >= 8) d = 0.0;
        d += __shfl_xor(d, 1, 64);            // partners of lanes 0-7 stay in 0-7
        d += __shfl_xor(d, 2, 64);
        d += __shfl_xor(d, 4, 64);
        if (p == 0) mn_s = d * 0.125;
    }
    __syncthreads();

    dif_stage<16, 16>(buf, W256, tid);        // span 64
    __syncthreads();
    dif_stage<4, 64>(buf, W256, tid);         // span 16
    __syncthreads();

    // ---- fused final stage (span 4, unit twiddles) + correction + gather ----
    // After 5 DIF stages output is base-4 digit-reversed: slot n holds X[rev(n)].
    // Thread t butterflies slots {4t..4t+3} (contiguous, same padded 16-group),
    // producing bins {R, R+256, R+512, R+768} with R = rev4(t). After the ^512
    // roll these are the four jj == R (mod 256). Inverse data map: valid iff
    // 96 <= jj <= 927 and (jj-95)%100 != 0; d = jj - 96 - (jj-96)/100.
    {
        const double mn001 = mn_s * 0.01;     // (mn*0.01)*jj == mn*0.01*jj (assoc)
        const int pb = PADIDX(4 * tid);       // 4t..4t+3 never cross a pad group
        float2 a = buf[pb];
        float2 b = buf[pb + 1];
        float2 c = buf[pb + 2];
        float2 d = buf[pb + 3];
        float2 t0 = make_float2(a.x + c.x, a.y + c.y);
        float2 t1 = make_float2(a.x - c.x, a.y - c.y);
        float2 t2 = make_float2(b.x + d.x, b.y + d.y);
        float2 t3 = make_float2(b.x - d.x, b.y - d.y);
        float2 y0 = make_float2(t0.x + t2.x, t0.y + t2.y);  // bin R      -> jj = R+512
        float2 y1 = make_float2(t1.x + t3.y, t1.y - t3.x);  // bin R+256  -> jj = R+768
        float2 y2 = make_float2(t0.x - t2.x, t0.y - t2.y);  // bin R+512  -> jj = R
        float2 y3 = make_float2(t1.x - t3.y, t1.y + t3.x);  // bin R+768  -> jj = R+256

        const int R = ((tid & 3) << 6) | (((tid >> 2) & 3) << 4) |
                      (((tid >> 4) & 3) << 2) | ((tid >> 6) & 3);

        float2* rout = (float2*)(out + (size_t)row * (2 * NSYMS));
        float2 ys[4] = { y2, y3, y0, y1 };    // ordered by jj = R, R+256, R+512, R+768
        #pragma unroll
        for (int k = 0; k < 4; k++) {
            const int jj = R + 256 * k;
            if (jj >= 96 && jj <= 927 && ((jj - 95) % 100) != 0) {
                const int dd = jj - 96 - (jj - 96) / 100;
                float2 z = ys[k];
                float th32 = (float)(128 * jj) * C32_TWOPI_1024;
                float ph = th32 - (float)(mn001 * (double)jj);
                float sn, cs;
                __sincosf(ph, &sn, &cs);
                rout[dd] = make_float2(z.x * cs - z.y * sn,
                                       z.x * sn + z.y * cs);
            }
        }
    }
}

extern "C" void kernel_launch(void* const* d_in, const int* in_sizes, int n_in,
                              void* d_out, int out_size, void* d_ws, size_t ws_size,
                              hipStream_t stream) {
    const float* in = (const float*)d_in[0];
    float* out = (float*)d_out;
    double2* Tg = (double2*)d_ws;                       // 256 * 16 B = 4096 B
    float2*  Wg = (float2*)((char*)d_ws + 4096);        // 256 *  8 B = 2048 B
    table_init<<<dim3(1), dim3(256), 0, stream>>>(Tg, Wg);
    ofdm_kernel<<<dim3(16 * 1024), dim3(NT), 0, stream>>>(in, out, Tg, Wg);
}